// Round 5
// baseline (96.826 us; speedup 1.0000x reference)
//
#include <hip/hip_runtime.h>

// EquivariantDense: out[b, i*O4+o] = sum_j sum_k w_{j+1}[b,o,k] * x[b, ((i+j)%4)*K + k]
// B=8, O4=1024, K=4096, N=4*K=16384. Output (B, 4*O4) fp32.
// Memory-bound: 512 MiB of weights streamed once per call.
//
// R5: occupancy fix. 512-thread blocks (8 waves) share one 64 KiB x-stage ->
// still 2 blocks/CU (LDS-limited) but 16 waves/CU = 4 waves/SIMD, doubling
// latency hiding for the vmcnt-batched HBM weight stream. Wave w: tensor
// j = w&3, row-half = w>>2. Block covers 8 output rows per tensor.

#define B_DIM 8
#define O4_DIM 1024
#define K_DIM 4096
#define N_DIM 16384
#define TILE_O 4

typedef float floatx4 __attribute__((ext_vector_type(4)));

__global__ __launch_bounds__(512) void eq_dense_kernel(
    const float* __restrict__ x,
    const float* __restrict__ w1,
    const float* __restrict__ w2,
    const float* __restrict__ w3,
    const float* __restrict__ w4,
    float* __restrict__ out)
{
    const int b    = blockIdx.y;
    const int tid  = threadIdx.x;
    const int wave = tid >> 6;          // 0..7
    const int j    = wave & 3;          // weight tensor
    const int half = wave >> 2;         // row-group within the block tile
    const int o0   = blockIdx.x * (2 * TILE_O) + half * TILE_O;
    const int lane = tid & 63;

    __shared__ floatx4 xs[N_DIM / 4];               // 64 KiB: all of x[b]
    __shared__ float red[2][4][TILE_O][4];          // [half][j][o][m]

    // Stage x[b] into LDS: 4096 float4 / 512 threads = 8 per thread, coalesced.
    {
        const floatx4* xg = reinterpret_cast<const floatx4*>(x + (size_t)b * N_DIM);
#pragma unroll
        for (int r = 0; r < 8; ++r)
            xs[r * 512 + tid] = xg[r * 512 + tid];
    }
    __syncthreads();

    const float* wsel = (j == 0) ? w1 : (j == 1) ? w2 : (j == 2) ? w3 : w4;
    const floatx4* wbase = reinterpret_cast<const floatx4*>(
        wsel + ((size_t)b * O4_DIM + o0) * K_DIM);

    float acc[TILE_O][4];
#pragma unroll
    for (int o = 0; o < TILE_O; ++o)
#pragma unroll
        for (int m = 0; m < 4; ++m)
            acc[o][m] = 0.0f;

    // K_DIM/4 = 1024 float4 per row; 64 lanes -> 16 iterations.
#pragma unroll 4
    for (int it = 0; it < 16; ++it) {
        const int idx = it * 64 + lane;
        floatx4 wv[TILE_O];
#pragma unroll
        for (int o = 0; o < TILE_O; ++o)
            wv[o] = wbase[o * 1024 + idx];      // VMEM: pure weight stream
        floatx4 xv[4];
#pragma unroll
        for (int m = 0; m < 4; ++m)
            xv[m] = xs[m * 1024 + idx];         // DS pipe, conflict-free b128
#pragma unroll
        for (int o = 0; o < TILE_O; ++o)
#pragma unroll
            for (int m = 0; m < 4; ++m) {
                acc[o][m] += wv[o].x * xv[m].x;
                acc[o][m] += wv[o].y * xv[m].y;
                acc[o][m] += wv[o].z * xv[m].z;
                acc[o][m] += wv[o].w * xv[m].w;
            }
    }

    // Wave-level butterfly reduction of all 16 accumulators (64 lanes).
#pragma unroll
    for (int o = 0; o < TILE_O; ++o)
#pragma unroll
        for (int m = 0; m < 4; ++m) {
            float v = acc[o][m];
            v += __shfl_xor(v, 32, 64);
            v += __shfl_xor(v, 16, 64);
            v += __shfl_xor(v, 8, 64);
            v += __shfl_xor(v, 4, 64);
            v += __shfl_xor(v, 2, 64);
            v += __shfl_xor(v, 1, 64);
            acc[o][m] = v;
        }

    if (lane == 0) {
#pragma unroll
        for (int o = 0; o < TILE_O; ++o)
#pragma unroll
            for (int m = 0; m < 4; ++m)
                red[half][j][o][m] = acc[o][m];
    }
    __syncthreads();

    // out[b, i*O4 + o0+o] = sum_j red[half][j][o][(i+j)&3]
    // 2 halves x 4 i-values x 4 rows = 32 outputs per block.
    if (tid < 32) {
        const int h = tid >> 4;
        const int i = (tid >> 2) & 3;
        const int o = tid & 3;
        float v = 0.0f;
#pragma unroll
        for (int jj = 0; jj < 4; ++jj)
            v += red[h][jj][o][(i + jj) & 3];
        const int orow = blockIdx.x * (2 * TILE_O) + h * TILE_O + o;
        out[(size_t)b * (4 * O4_DIM) + (size_t)i * O4_DIM + orow] = v;
    }
}

extern "C" void kernel_launch(void* const* d_in, const int* in_sizes, int n_in,
                              void* d_out, int out_size, void* d_ws, size_t ws_size,
                              hipStream_t stream) {
    const float* x  = (const float*)d_in[0];
    const float* w1 = (const float*)d_in[1];
    const float* w2 = (const float*)d_in[2];
    const float* w3 = (const float*)d_in[3];
    const float* w4 = (const float*)d_in[4];
    float* out = (float*)d_out;

    dim3 grid(O4_DIM / (2 * TILE_O), B_DIM);  // (128, 8) = 1024 blocks
    dim3 block(512);
    eq_dense_kernel<<<grid, block, 0, stream>>>(x, w1, w2, w3, w4, out);
}